// Round 1
// baseline (1489.172 us; speedup 1.0000x reference)
//
#include <hip/hip_runtime.h>
#include <hip/hip_bf16.h>
#include <math.h>

// Problem constants (from reference)
#define NTC 60      // nonterminals
#define TTC 120     // preterminals (terminals)
#define SD 512      // state dim
#define VV 10000    // vocab
#define BB 128      // batch
#define NN 40       // sentence length
#define STRW (NN*BB*NTC)   // 307200: stride of one width-slab in Lc/Rc

#define FINF __int_as_float(0x7f800000)

// ---------------------------------------------------------------------------
// Generic small GEMM: C[t,s] = maybe_relu( sum_k A[t,k]*W[s,k] + bias[s] )
//                              + res[t,s] + res2[t,s]
// K fixed = 512. Lane = output column s. 8 rows per thread (clamped).
// A-row addresses are wave-uniform (scalar-load friendly); W rows are
// per-lane sequential (L1-friendly, W is L2-resident).
// ---------------------------------------------------------------------------
__global__ __launch_bounds__(64) void gemm_tn(
    const float* __restrict__ A, const float* __restrict__ W,
    const float* __restrict__ bias, const float* __restrict__ res,
    const float* __restrict__ res2, float* __restrict__ C,
    int M, int Sout, int do_relu)
{
    int s  = blockIdx.x * 64 + threadIdx.x;
    int t0 = blockIdx.y * 8;
    if (s >= Sout) return;
    const float* wr = W + (size_t)s * SD;
    float acc[8];
#pragma unroll
    for (int tt = 0; tt < 8; ++tt) acc[tt] = 0.f;
    int tr[8];
#pragma unroll
    for (int tt = 0; tt < 8; ++tt) tr[tt] = min(t0 + tt, M - 1);

    for (int k = 0; k < SD; k += 4) {
        float4 wv = *(const float4*)(wr + k);
#pragma unroll
        for (int tt = 0; tt < 8; ++tt) {
            float4 av = *(const float4*)(A + tr[tt] * SD + k);
            acc[tt] += av.x * wv.x + av.y * wv.y + av.z * wv.z + av.w * wv.w;
        }
    }
    float bv = bias ? bias[s] : 0.f;
#pragma unroll
    for (int tt = 0; tt < 8; ++tt) {
        int t = t0 + tt;
        if (t < M) {
            float v = acc[tt] + bv;
            if (do_relu) v = fmaxf(v, 0.f);
            if (res)  v += res[t * Sout + s];
            if (res2) v += res2[t * Sout + s];
            C[t * Sout + s] = v;
        }
    }
}

// ---------------------------------------------------------------------------
// Vocab logits: logits[t,v] = sum_k g[t,k] * VE[k,v].  (120 x 10000)
// Lane = v (coalesced on VE rows); 30 rows of g per thread (uniform loads).
// ---------------------------------------------------------------------------
__global__ __launch_bounds__(64) void vocab_logits(
    const float* __restrict__ g, const float* __restrict__ VE,
    float* __restrict__ logits)
{
    int v  = blockIdx.x * 64 + threadIdx.x;
    int t0 = blockIdx.y * 30;
    bool act = v < VV;
    float acc[30];
#pragma unroll
    for (int tt = 0; tt < 30; ++tt) acc[tt] = 0.f;

    for (int k = 0; k < SD; k += 4) {
        float b0 = act ? VE[(k + 0) * VV + v] : 0.f;
        float b1 = act ? VE[(k + 1) * VV + v] : 0.f;
        float b2 = act ? VE[(k + 2) * VV + v] : 0.f;
        float b3 = act ? VE[(k + 3) * VV + v] : 0.f;
#pragma unroll
        for (int tt = 0; tt < 30; ++tt) {
            float4 gv = *(const float4*)(g + (t0 + tt) * SD + k);
            acc[tt] = fmaf(gv.x, b0, acc[tt]);
            acc[tt] = fmaf(gv.y, b1, acc[tt]);
            acc[tt] = fmaf(gv.z, b2, acc[tt]);
            acc[tt] = fmaf(gv.w, b3, acc[tt]);
        }
    }
    if (act) {
#pragma unroll
        for (int tt = 0; tt < 30; ++tt) logits[(t0 + tt) * VV + v] = acc[tt];
    }
}

// ---------------------------------------------------------------------------
// Row logsumexp of logits: lse[t] = max + log(sum(exp(row - max)))
// ---------------------------------------------------------------------------
__global__ __launch_bounds__(256) void lse_kernel(
    const float* __restrict__ logits, float* __restrict__ lse)
{
    int t = blockIdx.x;
    int tid = threadIdx.x;
    const float* row = logits + (size_t)t * VV;
    __shared__ float red[256];

    float mx = -FINF;
    for (int v = tid; v < VV; v += 256) mx = fmaxf(mx, row[v]);
    red[tid] = mx;
    __syncthreads();
    for (int st = 128; st > 0; st >>= 1) {
        if (tid < st) red[tid] = fmaxf(red[tid], red[tid + st]);
        __syncthreads();
    }
    float M = red[0];
    __syncthreads();

    float s = 0.f;
    for (int v = tid; v < VV; v += 256) s += __expf(row[v] - M);
    red[tid] = s;
    __syncthreads();
    for (int st = 128; st > 0; st >>= 1) {
        if (tid < st) red[tid] += red[tid + st];
        __syncthreads();
    }
    if (tid == 0) lse[t] = M + __logf(red[0]);
}

// ---------------------------------------------------------------------------
// root_ls[p] = log_softmax(root_emb @ rse[:NT].T)[p]   (one wave)
// ---------------------------------------------------------------------------
__global__ __launch_bounds__(64) void root_kernel(
    const float* __restrict__ root_emb, const float* __restrict__ rse,
    float* __restrict__ root_ls)
{
    int lane = threadIdx.x;
    float acc = 0.f;
    if (lane < NTC) {
        const float* rr = rse + (size_t)lane * SD;
        for (int k = 0; k < SD; k += 4) {
            float4 re = *(const float4*)(root_emb + k);
            float4 rv = *(const float4*)(rr + k);
            acc += re.x * rv.x + re.y * rv.y + re.z * rv.z + re.w * rv.w;
        }
    }
    float mx = (lane < NTC) ? acc : -FINF;
#pragma unroll
    for (int off = 32; off > 0; off >>= 1) mx = fmaxf(mx, __shfl_xor(mx, off));
    float e = (lane < NTC) ? __expf(acc - mx) : 0.f;
    float ssum = e;
#pragma unroll
    for (int off = 32; off > 0; off >>= 1) ssum += __shfl_xor(ssum, off);
    if (lane < NTC) root_ls[lane] = acc - (mx + __logf(ssum));
}

// ---------------------------------------------------------------------------
// Softmax over axis 0 (the 180 rules) for leftS / rightS, in place.
// blockIdx.x: 0 = left matrix, 1 = right matrix. Lane = column p.
// ---------------------------------------------------------------------------
__global__ __launch_bounds__(64) void softmax0_kernel(float* lrS)
{
    float* mat = lrS + (size_t)blockIdx.x * (180 * NTC);
    int p = threadIdx.x;
    if (p >= NTC) return;
    float mx = -FINF;
    for (int r = 0; r < 180; ++r) mx = fmaxf(mx, mat[r * NTC + p]);
    float s = 0.f;
    for (int r = 0; r < 180; ++r) s += __expf(mat[r * NTC + p] - mx);
    float inv = 1.f / s;
    for (int r = 0; r < 180; ++r)
        mat[r * NTC + p] = __expf(mat[r * NTC + p] - mx) * inv;
}

// ---------------------------------------------------------------------------
// Init: Lc[1,n,b,:] = logmm(unary[b,n,:], left_p), Rc[1,...] with right_p.
// unary fused: unary[b,n,t] = logits[t, word[b,n]] - lse[t].
// Block = (b,n) pair, 128 threads (wave0 -> L, wave1 -> R).
// ---------------------------------------------------------------------------
__global__ __launch_bounds__(128) void logmm1_kernel(
    const float* __restrict__ logits, const float* __restrict__ lse,
    const int* __restrict__ word, const float* __restrict__ lrS,
    float* __restrict__ Lc, float* __restrict__ Rc)
{
    int bid = blockIdx.x;          // b*NN + n
    int b = bid / NN, n = bid % NN;
    int tid = threadIdx.x;
    __shared__ float sh[128];
    __shared__ float shm[2];

    int wd = word[b * NN + n];
    float u = -FINF;
    if (tid < TTC) u = logits[(size_t)tid * VV + wd] - lse[tid];

    float wm = u;
#pragma unroll
    for (int off = 32; off > 0; off >>= 1) wm = fmaxf(wm, __shfl_xor(wm, off));
    if ((tid & 63) == 0) shm[tid >> 6] = wm;
    __syncthreads();
    float M = fmaxf(shm[0], shm[1]);

    sh[tid] = (tid < TTC) ? __expf(u - M) : 0.f;
    __syncthreads();

    int q = tid & 63;
    if (q < NTC) {
        // left_p = lrS + 60*60 ; right_p = lrS + 180*60 + 60*60
        const float* pm = (tid < 64) ? (lrS + NTC * NTC) : (lrS + 180 * NTC + NTC * NTC);
        float acc = 0.f;
        for (int t = 0; t < TTC; ++t) acc = fmaf(sh[t], pm[t * NTC + q], acc);
        float out = __logf(acc) + M;
        float* dst = (tid < 64) ? Lc : Rc;
        dst[((1 * NN + n) * BB + b) * NTC + q] = out;
    }
}

// ---------------------------------------------------------------------------
// One CKY width step. Block = (j,b) cell, one wave, lane = parent symbol p.
// beta[p] = logsumexp_k( Lc[k,j,b,p] + Rc[w-k,j+k,b,p] )  (online)
// If w < N: Lc[w,j,b,:] = logmm(beta, left_m); Rc[w,...] = logmm(beta, right_m)
// If w == N (j==0 only): beta_top[b,:] = beta.
// ---------------------------------------------------------------------------
__global__ __launch_bounds__(64) void beta_step(
    float* Lc, float* Rc, const float* __restrict__ lrS,
    float* __restrict__ beta_top, int w)
{
    int m = NN - w + 1;
    int j = blockIdx.x % m;
    int b = blockIdx.x / m;
    int lane = threadIdx.x;
    int p = (lane < NTC) ? lane : (NTC - 1);

    int lbase = (j * BB + b) * NTC + p;             // + k*STRW
    int rbase = w * STRW + j * BB * NTC + b * NTC + p; // + k*(BB*NTC - STRW)

    float mx = -FINF, sm = 0.f;
    for (int k = 1; k < w; ++k) {
        float lv = Lc[lbase + k * STRW];
        float rv = Rc[rbase + k * (BB * NTC) - k * STRW];
        float v = lv + rv;
        float nm = fmaxf(mx, v);
        sm = sm * __expf(mx - nm) + __expf(v - nm);
        mx = nm;
    }
    float beta = __logf(sm) + mx;

    if (w == NN) {
        if (lane < NTC) beta_top[b * NTC + lane] = beta;
        return;
    }

    float bm = (lane < NTC) ? beta : -FINF;
#pragma unroll
    for (int off = 32; off > 0; off >>= 1) bm = fmaxf(bm, __shfl_xor(bm, off));

    __shared__ float e[64];
    e[lane] = (lane < NTC) ? __expf(beta - bm) : 0.f;
    __syncthreads();

    const float* LM = lrS;               // left_m  = left[:60]
    const float* RM = lrS + 180 * NTC;   // right_m = right[:60]
    float accL = 0.f, accR = 0.f;
    for (int pp = 0; pp < NTC; ++pp) {
        float ep = e[pp];
        accL = fmaf(ep, LM[pp * NTC + lane < 180 * NTC ? pp * NTC + lane : 0], accL);
        accR = fmaf(ep, RM[pp * NTC + lane], accR);
    }
    if (lane < NTC) {
        int o = ((w * NN + j) * BB + b) * NTC + lane;
        Lc[o] = __logf(accL) + bm;
        Rc[o] = __logf(accR) + bm;
    }
}

// ---------------------------------------------------------------------------
// partition[b] = logsumexp_p(root_ls[p] + beta_top[b,p]); loss = -mean.
// d_out[0..127] = partition, d_out[128] = loss.
// ---------------------------------------------------------------------------
__global__ __launch_bounds__(128) void partition_kernel(
    const float* __restrict__ beta_top, const float* __restrict__ root_ls,
    float* __restrict__ out)
{
    int b = threadIdx.x;   // 128 threads, B=128
    float mx = -FINF;
    for (int p = 0; p < NTC; ++p)
        mx = fmaxf(mx, root_ls[p] + beta_top[b * NTC + p]);
    float s = 0.f;
    for (int p = 0; p < NTC; ++p)
        s += __expf(root_ls[p] + beta_top[b * NTC + p] - mx);
    float part = mx + __logf(s);
    out[b] = part;

    __shared__ float red[128];
    red[b] = part;
    __syncthreads();
    for (int st = 64; st > 0; st >>= 1) {
        if (b < st) red[b] += red[b + st];
        __syncthreads();
    }
    if (b == 0) out[BB] = -red[0] / (float)BB;
}

// ---------------------------------------------------------------------------
extern "C" void kernel_launch(void* const* d_in, const int* in_sizes, int n_in,
                              void* d_out, int out_size, void* d_ws, size_t ws_size,
                              hipStream_t stream)
{
    const int*   word     = (const int*)  d_in[0];
    const float* root_emb = (const float*)d_in[1];
    const float* rse      = (const float*)d_in[2];   // (180, 512)
    const float* VE       = (const float*)d_in[3];   // (512, 10000)
    const float* W0       = (const float*)d_in[4];
    const float* b0       = (const float*)d_in[5];
    const float* W1       = (const float*)d_in[6];   // (3,512,512)
    const float* b1       = (const float*)d_in[7];
    const float* W2       = (const float*)d_in[8];
    const float* b2       = (const float*)d_in[9];
    const float* lW       = (const float*)d_in[10];
    const float* lb       = (const float*)d_in[11];
    const float* rW       = (const float*)d_in[12];
    const float* rb       = (const float*)d_in[13];
    const float* pW       = (const float*)d_in[14];
    const float* pb       = (const float*)d_in[15];

    float* ws = (float*)d_ws;
    size_t o = 0;
    float* logits  = ws + o; o += (size_t)TTC * VV;     // 1,200,000
    float* lse     = ws + o; o += 128;
    float* h       = ws + o; o += TTC * SD;             // 61,440
    float* u       = ws + o; o += TTC * SD;
    float* g       = ws + o; o += TTC * SD;
    float* parent1 = ws + o; o += NTC * SD;             // 30,720
    float* leftH   = ws + o; o += 180 * SD;             // 92,160
    float* rightH  = ws + o; o += 180 * SD;
    float* lrS     = ws + o; o += 2 * 180 * NTC;        // 21,600 (left then right)
    float* root_ls = ws + o; o += 64;
    float* beta_top= ws + o; o += BB * NTC;             // 7,680
    float* Lc      = ws + o; o += (size_t)NN * NN * BB * NTC;  // 12,288,000
    float* Rc      = ws + o; o += (size_t)NN * NN * BB * NTC;

    const float* term_emb = rse + NTC * SD;  // rows 60..179

    dim3 g512(8, 15);   // Sout=512, M=120

    // h = term_emb @ W0.T + b0
    gemm_tn<<<g512, 64, 0, stream>>>(term_emb, W0, b0, nullptr, nullptr, h, TTC, SD, 0);
    // 3 residual blocks
    for (int i = 0; i < 3; ++i) {
        gemm_tn<<<g512, 64, 0, stream>>>(h, W1 + (size_t)i * SD * SD, b1 + i * SD,
                                         nullptr, nullptr, u, TTC, SD, 1);
        if (i < 2)
            gemm_tn<<<g512, 64, 0, stream>>>(u, W2 + (size_t)i * SD * SD, b2 + i * SD,
                                             h, nullptr, h, TTC, SD, 1);
        else  // fold the final "+ term_emb" into the last residual gemm -> g
            gemm_tn<<<g512, 64, 0, stream>>>(u, W2 + (size_t)2 * SD * SD, b2 + 2 * SD,
                                             h, term_emb, g, TTC, SD, 1);
    }

    // vocab logits + row logsumexp
    vocab_logits<<<dim3(157, 4), 64, 0, stream>>>(g, VE, logits);
    lse_kernel<<<TTC, 256, 0, stream>>>(logits, lse);

    // root log-softmax
    root_kernel<<<1, 64, 0, stream>>>(root_emb, rse, root_ls);

    // parent1 / leftH / rightH / left / right
    gemm_tn<<<dim3(8, 8), 64, 0, stream>>>(rse, pW, pb, rse, nullptr, parent1, NTC, SD, 1);
    gemm_tn<<<dim3(8, 23), 64, 0, stream>>>(rse, lW, lb, rse, nullptr, leftH, 180, SD, 1);
    gemm_tn<<<dim3(8, 23), 64, 0, stream>>>(rse, rW, rb, rse, nullptr, rightH, 180, SD, 1);
    gemm_tn<<<dim3(1, 23), 64, 0, stream>>>(leftH, parent1, nullptr, nullptr, nullptr,
                                            lrS, 180, NTC, 0);
    gemm_tn<<<dim3(1, 23), 64, 0, stream>>>(rightH, parent1, nullptr, nullptr, nullptr,
                                            lrS + 180 * NTC, 180, NTC, 0);
    softmax0_kernel<<<2, 64, 0, stream>>>(lrS);

    // inside algorithm
    logmm1_kernel<<<BB * NN, 128, 0, stream>>>(logits, lse, word, lrS, Lc, Rc);
    for (int w = 2; w <= NN; ++w) {
        int m = NN - w + 1;
        beta_step<<<m * BB, 64, 0, stream>>>(Lc, Rc, lrS, beta_top, w);
    }
    partition_kernel<<<1, 128, 0, stream>>>(beta_top, root_ls, (float*)d_out);
}